// Round 3
// baseline (235.944 us; speedup 1.0000x reference)
//
#include <hip/hip_runtime.h>

// Parametric LIF forward (spike output only).
// x: [B=64, T=64, N=8192] fp32.  out: same shape, values in {0,1}.
// Recurrence per (b,n):  u = last*sig + x[t];  s = (u >= th);
//                        last = (u + lamb*(u-last)) * (1-s)
//
// History:
//  R3: f2, UN=8, 1-deep, fully unrolled, 16 waves/CU -> 73.7us (3.3 TB/s).
//  R4: f4 + 2-deep: compiler collapsed pipeline (VGPR=32), TLP halved -> 88us.
//  R5: f2 + rolled 2-deep: collapsed again (VGPR=40, 3 bufs need 48) -> 81us.
//  Conclusion: NOT latency-depth-bound. In-flight bytes/CU (64KB) >> needed
//  (~9KB); VALUBusy 8% matches pure-BW prediction; yet only ~50% of the
//  6.3 TB/s copy ceiling. Remaining delta vs known-peak kernels (fills 6.7,
//  m13 copy 6.29): they run MONO-directional or coarse-grained streams; we
//  fine-grain interleave a read stream and a write stream of 512-B islands
//  (32KB-strided t-walk) in every wave -> R/W turnaround + sub-page scatter.
// R6: phase-split. Spikes are bits: pack 64t x 2comp into 4 u32 registers.
//  Phase A = R3's unrolled load+recurrence loop with NO stores (read-only
//  stream; compiler free to hoist loads deep -- nothing to order against).
//  Phase B = pure store blast (unpack bits -> f2 {0,1}).
//  Arithmetic per element unchanged (same *_rn ops, s as float) -> spike
//  outputs bitwise identical, absmax 0. nt stores keep the write stream out
//  of L3 so read-residency (FETCH showed ~50% L3 hits) is preserved.

#define LIF_B 64
#define LIF_T 64
#define LIF_N 8192
#define NV2 (LIF_N / 2)        // float2s per row = 4096
#define UN 8                   // t-steps per load stage
#define NSTAGE (LIF_T / UN)    // 8

typedef float f2 __attribute__((ext_vector_type(2)));

__global__ __launch_bounds__(256, 4) void lif_fwd_kernel(
    const f2* __restrict__ x,
    const float* __restrict__ tau_p,
    const float* __restrict__ lamb_p,
    const float* __restrict__ th_p,
    f2* __restrict__ out)
{
    const int tid = blockIdx.x * blockDim.x + threadIdx.x;   // 0 .. B*NV2-1
    const int b   = tid >> 12;                               // / NV2 (4096)
    const int n2  = tid & (NV2 - 1);

    const float sig  = 1.0f / (1.0f + expf(-tau_p[0]));      // 0.5 exact
    const float lamb = lamb_p[0];
    const float th   = th_p[0];

    float lx = 0.0f, ly = 0.0f;                              // carried state
    const size_t base = (size_t)b * LIF_T * NV2 + n2;

    f2 cur[UN], nxt[UN];
    unsigned int bits[4] = {0u, 0u, 0u, 0u};   // bit (t&15)*2+comp of word t>>4

    // ---------------- Phase A: load + recurrence (read-only stream) --------
#pragma unroll
    for (int i = 0; i < UN; ++i)
        cur[i] = x[base + (size_t)i * NV2];

#pragma unroll
    for (int k = 0; k < NSTAGE; ++k) {
        if (k + 1 < NSTAGE) {
#pragma unroll
            for (int i = 0; i < UN; ++i)
                nxt[i] = x[base + (size_t)((k + 1) * UN + i) * NV2];
        }

#pragma unroll
        for (int i = 0; i < UN; ++i) {
            const int t = k * UN + i;
            f2 v = cur[i];
            {
                float u = __fadd_rn(__fmul_rn(lx, sig), v.x);
                bool  c = (u >= th);
                float s = c ? 1.0f : 0.0f;
                lx = __fmul_rn(__fadd_rn(u, __fmul_rn(lamb, __fsub_rn(u, lx))),
                               __fsub_rn(1.0f, s));
                bits[t >> 4] |= c ? (1u << ((t & 15) * 2)) : 0u;
            }
            {
                float u = __fadd_rn(__fmul_rn(ly, sig), v.y);
                bool  c = (u >= th);
                float s = c ? 1.0f : 0.0f;
                ly = __fmul_rn(__fadd_rn(u, __fmul_rn(lamb, __fsub_rn(u, ly))),
                               __fsub_rn(1.0f, s));
                bits[t >> 4] |= c ? (1u << ((t & 15) * 2 + 1)) : 0u;
            }
        }

#pragma unroll
        for (int i = 0; i < UN; ++i)
            cur[i] = nxt[i];
    }

    // ---------------- Phase B: store blast (write-only stream) -------------
#pragma unroll
    for (int t = 0; t < LIF_T; ++t) {
        const unsigned int w = bits[t >> 4];
        f2 sv;
        sv.x = ((w >> ((t & 15) * 2))     & 1u) ? 1.0f : 0.0f;
        sv.y = ((w >> ((t & 15) * 2 + 1)) & 1u) ? 1.0f : 0.0f;
        __builtin_nontemporal_store(sv, &out[base + (size_t)t * NV2]);
    }
}

extern "C" void kernel_launch(void* const* d_in, const int* in_sizes, int n_in,
                              void* d_out, int out_size, void* d_ws, size_t ws_size,
                              hipStream_t stream) {
    (void)in_sizes; (void)n_in; (void)out_size; (void)d_ws; (void)ws_size;

    const f2*    x     = (const f2*)d_in[0];
    const float* tau_p = (const float*)d_in[1];
    const float* lamb  = (const float*)d_in[2];
    const float* th    = (const float*)d_in[3];
    f2*          out   = (f2*)d_out;

    const int total_threads = LIF_B * NV2;           // 262144
    const int block = 256;
    const int grid  = total_threads / block;         // 1024
    lif_fwd_kernel<<<grid, block, 0, stream>>>(x, tau_p, lamb, th, out);
}

// Round 5
// 235.933 us; speedup vs baseline: 1.0000x; 1.0000x over previous
//
#include <hip/hip_runtime.h>

// Parametric LIF forward (spike output only).
// x: [B=64, T=64, N=8192] fp32.  out: same shape, values in {0,1}.
// Recurrence per (b,n):  u = last*sig + x[t];  s = (u >= th);
//                        last = (u + lamb*(u-last)) * (1-s)
//
// History:
//  R3: f2, UN=8, 1-deep cur/nxt, 16 waves/CU -> 73.7us (3.3 TB/s logical).
//  R4: f4 + 2-deep: compiler collapsed pipeline (VGPR=32) -> 88us.
//  R5: rolled 2-deep: collapsed again (VGPR=40) -> 81us.
//  R6: phase-split (bit-pack, read phase then write phase) -> ~75us, no change.
//  R7: (this kernel) bench infra failed twice -- resubmitting unchanged.
//  Counters across rounds: HBM 2.4 TB/s actual (38% of ceiling), VALU 8%,
//  occupancy 33%, LDS 0 -> latency-bound with ~11k-cy effective latency
//  (12x cold miss). Theory: the per-thread t-stride is exactly 32 KiB =
//  the channel/TCC-slice alias period (256B granule x ~128 slices), so a
//  wave's 8 in-flight loads (8 t-rows x same 512-B window) all land on the
//  SAME ~2 slices; stores likewise. Per-wave traffic serializes through one
//  slice queue -> huge effective latency at low aggregate BW. Pipeline depth
//  / TLP / phase-split never changed this concentration -- consistent with
//  all three null results.
// R7: widen per-wave contiguous islands. Each lane owns TWO ADJACENT f4
//  columns (lane l of wave w: f4-cols wavebase + l and wavebase + 64 + l),
//  so one wave covers 512 consecutive f4 = 2 KiB per t-row (8 slices), a
//  block covers 8 KiB. A stage's 8 in-flight loads now spread over 8+
//  slices instead of 2. Grid: 256 blocks x 256 threads = 4 waves/CU (fills
//  hit 6.7 TB/s at ~3 waves/CU, so TLP suffices). Skeleton = R3's proven
//  1-deep cur/nxt full unroll (the 2-buffer shape the compiler keeps).
//  Per-column arithmetic identical (*_rn ops, no FMA) -> absmax 0.

#define LIF_B 64
#define LIF_T 64
#define LIF_N 8192
#define NV4 (LIF_N / 4)        // f4 per row = 2048
#define UN 4                   // t-steps per stage
#define NSTAGE (LIF_T / UN)    // 16

typedef float f4 __attribute__((ext_vector_type(4)));

// One LIF step on one f4 component. ST = state f4, VV = input f4, SS = out f4.
#define LIF_COMP(ST, VV, SS, C)                                                \
    {                                                                          \
        float u = __fadd_rn(__fmul_rn(ST.C, sig), VV.C);                       \
        float s = (u >= th) ? 1.0f : 0.0f;                                     \
        ST.C = __fmul_rn(__fadd_rn(u, __fmul_rn(lamb, __fsub_rn(u, ST.C))),    \
                         __fsub_rn(1.0f, s));                                  \
        SS.C = s;                                                              \
    }
#define LIF_F4(ST, VV, SS)                                                     \
    LIF_COMP(ST, VV, SS, x) LIF_COMP(ST, VV, SS, y)                            \
    LIF_COMP(ST, VV, SS, z) LIF_COMP(ST, VV, SS, w)

__global__ __launch_bounds__(256) void lif_fwd_kernel(
    const f4* __restrict__ x,
    const float* __restrict__ tau_p,
    const float* __restrict__ lamb_p,
    const float* __restrict__ th_p,
    f4* __restrict__ out)
{
    // Thread -> column mapping: block owns 512 consecutive f4 of one b-row
    // window; wave owns 128 consecutive f4 (2 KiB/t); lane owns 2 f4, 64 apart.
    const int w  = threadIdx.x >> 6;                 // wave in block, 0..3
    const int l  = threadIdx.x & 63;                 // lane
    const int b  = blockIdx.x >> 2;                  // 64 batches
    const int c0 = ((blockIdx.x & 3) << 9) | (w << 7) | l;   // f4 col, seg 0
    // seg 1 col = c0 + 64

    const float sig  = 1.0f / (1.0f + expf(-tau_p[0]));      // 0.5 exact
    const float lamb = lamb_p[0];
    const float th   = th_p[0];

    const size_t base = (size_t)b * (LIF_T * NV4) + c0;

    f4 stA = {0.0f, 0.0f, 0.0f, 0.0f};               // state, seg 0
    f4 stB = {0.0f, 0.0f, 0.0f, 0.0f};               // state, seg 1

    f4 cur[UN][2], nxt[UN][2];

    // Prologue: stage 0 in flight.
#pragma unroll
    for (int i = 0; i < UN; ++i) {
        const size_t o = base + (size_t)i * NV4;
        cur[i][0] = x[o];
        cur[i][1] = x[o + 64];
    }

#pragma unroll
    for (int k = 0; k < NSTAGE; ++k) {
        // 1) Prefetch stage k+1 first (loads older than this stage's stores
        //    in the vmcnt FIFO -> next stage's wait drains no store acks).
        if (k + 1 < NSTAGE) {
#pragma unroll
            for (int i = 0; i < UN; ++i) {
                const size_t o = base + (size_t)((k + 1) * UN + i) * NV4;
                nxt[i][0] = x[o];
                nxt[i][1] = x[o + 64];
            }
        }

        // 2) Compute + store stage k.
#pragma unroll
        for (int i = 0; i < UN; ++i) {
            const size_t o = base + (size_t)(k * UN + i) * NV4;
            f4 s0, s1;
            LIF_F4(stA, cur[i][0], s0)
            LIF_F4(stB, cur[i][1], s1)
            __builtin_nontemporal_store(s0, &out[o]);
            __builtin_nontemporal_store(s1, &out[o + 64]);
        }

        // 3) Rotate (register renames after full unroll).
#pragma unroll
        for (int i = 0; i < UN; ++i) {
            cur[i][0] = nxt[i][0];
            cur[i][1] = nxt[i][1];
        }
    }
}

extern "C" void kernel_launch(void* const* d_in, const int* in_sizes, int n_in,
                              void* d_out, int out_size, void* d_ws, size_t ws_size,
                              hipStream_t stream) {
    (void)in_sizes; (void)n_in; (void)out_size; (void)d_ws; (void)ws_size;

    const f4*    x     = (const f4*)d_in[0];
    const float* tau_p = (const float*)d_in[1];
    const float* lamb  = (const float*)d_in[2];
    const float* th    = (const float*)d_in[3];
    f4*          out   = (f4*)d_out;

    const int block = 256;
    const int grid  = 256;   // 64 b x 4 column-quads; 4 waves/CU
    lif_fwd_kernel<<<grid, block, 0, stream>>>(x, tau_p, lamb, th, out);
}